// Round 1
// baseline (18655.588 us; speedup 1.0000x reference)
//
#include <hip/hip_runtime.h>
#include <hip/hip_bf16.h>
#include <math.h>

// Problem constants
#define SL 256
#define BS 64
#define DI 1024
#define HH 512
#define TT 17
#define NR (SL*BS)        // 16384 rows
#define G4 (4*HH)         // 2048 gates
#define C2 (2*HH)         // 1024 channels

__device__ __forceinline__ float sigm(float x) { return 1.f / (1.f + expf(-x)); }

// ---------------------------------------------------------------------------
// Transpose w_hh (2048x512) -> whhT (512x2048)
// ---------------------------------------------------------------------------
__global__ void transpose_whh(const float* __restrict__ src, float* __restrict__ dst)
{
    __shared__ float tile[32][33];
    const int bx = blockIdx.x;           // k tile: 512/32 = 16
    const int by = blockIdx.y;           // n tile: 2048/32 = 64
    const int tx = threadIdx.x, ty = threadIdx.y;   // 32 x 8
    int x = bx * 32 + tx;                // k
    int y = by * 32 + ty;                // n
    #pragma unroll
    for (int i = 0; i < 32; i += 8)
        tile[ty + i][tx] = src[(size_t)(y + i) * HH + x];
    __syncthreads();
    int x2 = by * 32 + tx;               // n
    int y2 = bx * 32 + ty;               // k
    #pragma unroll
    for (int i = 0; i < 32; i += 8)
        dst[(size_t)(y2 + i) * G4 + x2] = tile[tx][ty + i];
}

// ---------------------------------------------------------------------------
// xg = X(16384x1024) @ W^T(1024x2048) + b1 + b2   (fp32, 128x128x16 tiles)
// ---------------------------------------------------------------------------
__global__ __launch_bounds__(256) void gemm_xg(
    const float* __restrict__ A,    // [16384][1024]
    const float* __restrict__ W,    // [2048][1024]
    const float* __restrict__ b1,
    const float* __restrict__ b2,
    float* __restrict__ C)          // [16384][2048]
{
    __shared__ float As[16][128];
    __shared__ float Bs[16][128];
    const int tid = threadIdx.x;
    const int m0 = blockIdx.x * 128;
    const int n0 = blockIdx.y * 128;
    const int tm = tid >> 4;        // 0..15
    const int tn = tid & 15;        // 0..15
    const int lr = tid >> 2;        // 0..63
    const int lc = (tid & 3) * 4;   // 0,4,8,12

    float acc[8][8];
    #pragma unroll
    for (int i = 0; i < 8; i++)
        #pragma unroll
        for (int j = 0; j < 8; j++) acc[i][j] = 0.f;

    for (int kt = 0; kt < DI; kt += 16) {
        #pragma unroll
        for (int p = 0; p < 2; p++) {
            float4 v = *(const float4*)(A + (size_t)(m0 + p * 64 + lr) * DI + kt + lc);
            As[lc + 0][p * 64 + lr] = v.x;
            As[lc + 1][p * 64 + lr] = v.y;
            As[lc + 2][p * 64 + lr] = v.z;
            As[lc + 3][p * 64 + lr] = v.w;
            float4 w = *(const float4*)(W + (size_t)(n0 + p * 64 + lr) * DI + kt + lc);
            Bs[lc + 0][p * 64 + lr] = w.x;
            Bs[lc + 1][p * 64 + lr] = w.y;
            Bs[lc + 2][p * 64 + lr] = w.z;
            Bs[lc + 3][p * 64 + lr] = w.w;
        }
        __syncthreads();
        #pragma unroll
        for (int kk = 0; kk < 16; kk++) {
            float4 a0 = *(const float4*)&As[kk][tm * 8];
            float4 a1 = *(const float4*)&As[kk][tm * 8 + 4];
            float4 bv0 = *(const float4*)&Bs[kk][tn * 8];
            float4 bv1 = *(const float4*)&Bs[kk][tn * 8 + 4];
            float a[8] = {a0.x, a0.y, a0.z, a0.w, a1.x, a1.y, a1.z, a1.w};
            float b[8] = {bv0.x, bv0.y, bv0.z, bv0.w, bv1.x, bv1.y, bv1.z, bv1.w};
            #pragma unroll
            for (int i = 0; i < 8; i++)
                #pragma unroll
                for (int j = 0; j < 8; j++)
                    acc[i][j] = fmaf(a[i], b[j], acc[i][j]);
        }
        __syncthreads();
    }
    #pragma unroll
    for (int i = 0; i < 8; i++) {
        const int m = m0 + tm * 8 + i;
        float* Crow = C + (size_t)m * G4 + n0 + tn * 8;
        #pragma unroll
        for (int j = 0; j < 8; j++) {
            const int n = n0 + tn * 8 + j;
            Crow[j] = acc[i][j] + b1[n] + b2[n];
        }
    }
}

// ---------------------------------------------------------------------------
// LSTM recurrence: one block per batch element, 512 threads.
// thread j owns hidden unit j (c in reg), computes gates 4j..4j+3 in matmul.
// ---------------------------------------------------------------------------
__global__ __launch_bounds__(512) void lstm_rec(
    const float* __restrict__ xg,     // [256][64][2048]
    const float* __restrict__ whhT,   // [512][2048]
    float* __restrict__ out,          // [256*64][1024]
    int reverse, int col_off)
{
    __shared__ float h_sh[HH];
    __shared__ float g_sh[G4];
    const int b = blockIdx.x;
    const int tid = threadIdx.x;

    h_sh[tid] = 0.f;
    float c = 0.f;
    __syncthreads();

    for (int step = 0; step < SL; ++step) {
        const int t = reverse ? (SL - 1 - step) : step;
        const float* xr = xg + (size_t)(t * BS + b) * G4;
        float4 acc = *(const float4*)(xr + 4 * tid);
        const float* wp = whhT + 4 * tid;
        #pragma unroll 8
        for (int k = 0; k < HH; k++) {
            const float hk = h_sh[k];
            const float4 w = *(const float4*)(wp + (size_t)k * G4);
            acc.x = fmaf(hk, w.x, acc.x);
            acc.y = fmaf(hk, w.y, acc.y);
            acc.z = fmaf(hk, w.z, acc.z);
            acc.w = fmaf(hk, w.w, acc.w);
        }
        *(float4*)(g_sh + 4 * tid) = acc;
        __syncthreads();
        const float i_ = sigm(g_sh[tid]);
        const float f_ = sigm(g_sh[tid + HH]);
        const float g_ = tanhf(g_sh[tid + 2 * HH]);
        const float o_ = sigm(g_sh[tid + 3 * HH]);
        c = f_ * c + i_ * g_;
        const float h = o_ * tanhf(c);
        out[(size_t)(t * BS + b) * C2 + col_off + tid] = h;
        h_sh[tid] = h;
        __syncthreads();
    }
}

// ---------------------------------------------------------------------------
// BatchNorm stats: one block per channel (two-pass mean/var)
// ---------------------------------------------------------------------------
__global__ __launch_bounds__(256) void bn_stats(
    const float* __restrict__ X, float* __restrict__ mean, float* __restrict__ istd)
{
    const int ch = blockIdx.x, tid = threadIdx.x;
    __shared__ float red[256];
    float s = 0.f;
    for (int r = tid; r < NR; r += 256) s += X[(size_t)r * C2 + ch];
    red[tid] = s; __syncthreads();
    for (int o = 128; o; o >>= 1) { if (tid < o) red[tid] += red[tid + o]; __syncthreads(); }
    const float mu = red[0] * (1.f / NR);
    __syncthreads();
    float v = 0.f;
    for (int r = tid; r < NR; r += 256) { const float d = X[(size_t)r * C2 + ch] - mu; v = fmaf(d, d, v); }
    red[tid] = v; __syncthreads();
    for (int o = 128; o; o >>= 1) { if (tid < o) red[tid] += red[tid + o]; __syncthreads(); }
    if (tid == 0) { mean[ch] = mu; istd[ch] = rsqrtf(red[0] * (1.f / NR) + 1e-5f); }
}

// ---------------------------------------------------------------------------
// Fold BN into linear: Wf[t][c] = lin_w[t][c]*gamma[c]*istd[c]
//                      ct[t]    = lin_b[t] + sum_c (beta - mean*gamma*istd)*lin_w
// ---------------------------------------------------------------------------
__global__ void fold_lin(const float* __restrict__ lin_w, const float* __restrict__ lin_b,
                         const float* __restrict__ gamma, const float* __restrict__ beta,
                         const float* __restrict__ mean, const float* __restrict__ istd,
                         float* __restrict__ Wf, float* __restrict__ ct)
{
    const int t = blockIdx.x, tid = threadIdx.x;
    __shared__ float red[256];
    float acc = 0.f;
    for (int cc = tid; cc < C2; cc += 256) {
        const float w = lin_w[t * C2 + cc];
        const float g = gamma[cc] * istd[cc];
        Wf[t * C2 + cc] = w * g;
        acc = fmaf(beta[cc] - mean[cc] * g, w, acc);
    }
    red[tid] = acc; __syncthreads();
    for (int o = 128; o; o >>= 1) { if (tid < o) red[tid] += red[tid + o]; __syncthreads(); }
    if (tid == 0) ct[t] = red[0] + lin_b[t];
}

// ---------------------------------------------------------------------------
// Emission logits E[b][s][t] = sum_c X[r][c]*Wf[t][c] + ct[t]   (wave per row)
// ---------------------------------------------------------------------------
__global__ __launch_bounds__(256) void emit_logits(
    const float* __restrict__ X, const float* __restrict__ Wf,
    const float* __restrict__ ct, float* __restrict__ E)
{
    const int r = blockIdx.x * 4 + (threadIdx.x >> 6);
    const int lane = threadIdx.x & 63;
    const float* xr = X + (size_t)r * C2;
    float acc[TT];
    #pragma unroll
    for (int t = 0; t < TT; t++) acc[t] = 0.f;
    for (int i = 0; i < C2 / 64; i++) {
        const int cc = i * 64 + lane;
        const float xv = xr[cc];
        #pragma unroll
        for (int t = 0; t < TT; t++) acc[t] = fmaf(xv, Wf[t * C2 + cc], acc[t]);
    }
    #pragma unroll
    for (int t = 0; t < TT; t++)
        for (int off = 32; off; off >>= 1) acc[t] += __shfl_xor(acc[t], off);
    if (lane == 0) {
        const int b = r & (BS - 1), s = r >> 6;
        float* Er = E + ((size_t)b * SL + s) * TT;
        #pragma unroll
        for (int t = 0; t < TT; t++) Er[t] = acc[t] + ct[t];
    }
}

// ---------------------------------------------------------------------------
// CRF log-likelihood per batch element: res[b] = num - Z   (one wave / block)
// ---------------------------------------------------------------------------
__global__ __launch_bounds__(64) void crf_llh(
    const float* __restrict__ E, const int* __restrict__ mask,
    const int* __restrict__ labels, const float* __restrict__ startv,
    const float* __restrict__ endv, const float* __restrict__ trans,
    float* __restrict__ res)
{
    const int b = blockIdx.x, lane = threadIdx.x;
    __shared__ float tr[TT][TT];
    for (int i = lane; i < TT * TT; i += 64) tr[i / TT][i % TT] = trans[i];
    __syncthreads();
    const float* Eb = E + (size_t)b * SL * TT;
    const int j = (lane < TT) ? lane : 0;

    float alpha = -1e30f;
    if (lane < TT) alpha = startv[lane] + Eb[lane];

    // numerator pieces (parallel over t)
    float numacc = 0.f; int len = 0;
    for (int t = lane; t < SL; t += 64) {
        const int mt = mask[t * BS + b];
        len += (mt != 0);
        if (t >= 1 && mt) {
            const int yp = labels[(t - 1) * BS + b];
            const int yt = labels[t * BS + b];
            numacc += tr[yp][yt] + Eb[t * TT + yt];
        }
    }
    for (int off = 32; off; off >>= 1) {
        numacc += __shfl_xor(numacc, off);
        len += __shfl_xor(len, off);
    }

    // forward algorithm
    for (int t = 1; t < SL; ++t) {
        const int mt = mask[t * BS + b];   // wave-uniform
        if (mt) {
            float av[TT];
            #pragma unroll
            for (int i = 0; i < TT; i++) av[i] = __shfl(alpha, i);
            const float e = (lane < TT) ? Eb[t * TT + lane] : 0.f;
            float mx = -1e30f;
            #pragma unroll
            for (int i = 0; i < TT; i++) mx = fmaxf(mx, av[i] + tr[i][j]);
            float s = 0.f;
            #pragma unroll
            for (int i = 0; i < TT; i++) s += expf(av[i] + tr[i][j] - mx);
            const float nxt = mx + logf(s) + e;
            if (lane < TT) alpha = nxt;
        }
    }
    // Z = logsumexp(alpha + end)
    float v = (lane < TT) ? alpha + endv[lane] : -1e30f;
    float mx = v;
    for (int off = 32; off; off >>= 1) mx = fmaxf(mx, __shfl_xor(mx, off));
    float se = (lane < TT) ? expf(v - mx) : 0.f;
    for (int off = 32; off; off >>= 1) se += __shfl_xor(se, off);
    const float Z = mx + logf(se);

    if (lane == 0) {
        const int y0 = labels[b];
        float num = startv[y0] + Eb[y0] + numacc;
        const int last = len - 1;
        const int yl = labels[last * BS + b];
        num += endv[yl];
        res[b] = num - Z;
    }
}

__global__ __launch_bounds__(64) void loss_reduce(const float* __restrict__ res, float* __restrict__ out)
{
    const int lane = threadIdx.x;
    float v = res[lane];
    for (int off = 32; off; off >>= 1) v += __shfl_xor(v, off);
    if (lane == 0) out[0] = -v;
}

// ---------------------------------------------------------------------------
// Viterbi per batch element (one wave / block); preds written as float
// ---------------------------------------------------------------------------
__global__ __launch_bounds__(64) void viterbi(
    const float* __restrict__ E, const int* __restrict__ mask,
    const float* __restrict__ startv, const float* __restrict__ endv,
    const float* __restrict__ trans, float* __restrict__ preds)
{
    const int b = blockIdx.x, lane = threadIdx.x;
    __shared__ float tr[TT][TT];
    __shared__ unsigned char bp[SL][TT];
    for (int i = lane; i < TT * TT; i += 64) tr[i / TT][i % TT] = trans[i];
    __syncthreads();
    const float* Eb = E + (size_t)b * SL * TT;
    const int j = (lane < TT) ? lane : 0;

    float score = (lane < TT) ? startv[lane] + Eb[lane] : -1e30f;
    for (int t = 1; t < SL; ++t) {
        float av[TT];
        #pragma unroll
        for (int i = 0; i < TT; i++) av[i] = __shfl(score, i);
        float best = -1e30f; int bi = 0;
        #pragma unroll
        for (int i = 0; i < TT; i++) {
            const float cand = av[i] + tr[i][j];
            if (cand > best) { best = cand; bi = i; }   // strict > => first max (jnp.argmax)
        }
        const int mt = mask[t * BS + b];
        if (lane < TT) {
            bp[t][lane] = (unsigned char)bi;
            if (mt) score = best + Eb[t * TT + lane];
        }
    }
    // last_tag = argmax(score + end), first-index tiebreak
    float v = (lane < TT) ? score + endv[lane] : -1e30f;
    float mx = v;
    for (int off = 32; off; off >>= 1) mx = fmaxf(mx, __shfl_xor(mx, off));
    unsigned long long ball = __ballot(v == mx);
    const int last_tag = __ffsll((unsigned long long)ball) - 1;
    __syncthreads();

    if (lane == 0) {
        int tag = last_tag;
        float* pb = preds + (size_t)b * SL;
        for (int t = SL - 1; t >= 1; --t) {
            const int mt = mask[t * BS + b];
            pb[t] = mt ? (float)tag : 0.f;
            if (mt) tag = bp[t][tag];
        }
        pb[0] = mask[b] ? (float)tag : 0.f;
    }
}

// ---------------------------------------------------------------------------
extern "C" void kernel_launch(void* const* d_in, const int* in_sizes, int n_in,
                              void* d_out, int out_size, void* d_ws, size_t ws_size,
                              hipStream_t stream)
{
    const float* word    = (const float*)d_in[0];
    const int*   mask    = (const int*)  d_in[1];
    const int*   labels  = (const int*)  d_in[2];
    const float* w_ih_f  = (const float*)d_in[3];
    const float* w_hh_f  = (const float*)d_in[4];
    const float* b_ih_f  = (const float*)d_in[5];
    const float* b_hh_f  = (const float*)d_in[6];
    const float* w_ih_b  = (const float*)d_in[7];
    const float* w_hh_b  = (const float*)d_in[8];
    const float* b_ih_b  = (const float*)d_in[9];
    const float* b_hh_b  = (const float*)d_in[10];
    const float* gamma   = (const float*)d_in[11];
    const float* beta    = (const float*)d_in[12];
    const float* lin_w   = (const float*)d_in[13];
    const float* lin_b   = (const float*)d_in[14];
    const float* c_start = (const float*)d_in[15];
    const float* c_end   = (const float*)d_in[16];
    const float* c_trans = (const float*)d_in[17];
    float* out = (float*)d_out;
    (void)in_sizes; (void)n_in; (void)out_size; (void)ws_size;

    char* ws = (char*)d_ws;
    size_t off = 0;
    auto alloc = [&](size_t bytes) {
        void* p = ws + off;
        off += (bytes + 255) & ~(size_t)255;
        return p;
    };
    float* XG   = (float*)alloc((size_t)NR * G4 * 4);   // 128 MB (reused f/b)
    float* WT_F = (float*)alloc((size_t)HH * G4 * 4);   // 4 MB
    float* WT_B = (float*)alloc((size_t)HH * G4 * 4);   // 4 MB
    float* LOUT = (float*)alloc((size_t)NR * C2 * 4);   // 64 MB
    float* MEAN = (float*)alloc(C2 * 4);
    float* ISTD = (float*)alloc(C2 * 4);
    float* WF   = (float*)alloc(TT * C2 * 4);
    float* CT   = (float*)alloc(TT * 4);
    float* Ebuf = (float*)alloc((size_t)BS * SL * TT * 4);
    float* RES  = (float*)alloc(BS * 4);
    // total ~211 MB

    transpose_whh<<<dim3(16, 64), dim3(32, 8), 0, stream>>>(w_hh_f, WT_F);
    transpose_whh<<<dim3(16, 64), dim3(32, 8), 0, stream>>>(w_hh_b, WT_B);

    // forward direction
    gemm_xg<<<dim3(NR / 128, G4 / 128), 256, 0, stream>>>(word, w_ih_f, b_ih_f, b_hh_f, XG);
    lstm_rec<<<BS, HH, 0, stream>>>(XG, WT_F, LOUT, 0, 0);
    // backward direction (reuses XG)
    gemm_xg<<<dim3(NR / 128, G4 / 128), 256, 0, stream>>>(word, w_ih_b, b_ih_b, b_hh_b, XG);
    lstm_rec<<<BS, HH, 0, stream>>>(XG, WT_B, LOUT, 1, HH);

    bn_stats<<<C2, 256, 0, stream>>>(LOUT, MEAN, ISTD);
    fold_lin<<<TT, 256, 0, stream>>>(lin_w, lin_b, gamma, beta, MEAN, ISTD, WF, CT);
    emit_logits<<<NR / 4, 256, 0, stream>>>(LOUT, WF, CT, Ebuf);

    crf_llh<<<BS, 64, 0, stream>>>(Ebuf, mask, labels, c_start, c_end, c_trans, RES);
    loss_reduce<<<1, 64, 0, stream>>>(RES, out);
    viterbi<<<BS, 64, 0, stream>>>(Ebuf, mask, c_start, c_end, c_trans, out + 1);
}